// Round 1
// baseline (794.388 us; speedup 1.0000x reference)
//
#include <hip/hip_runtime.h>
#include <math.h>
#include <stdint.h>

// HashEmbedder, round 3: single fused kernel.
// One thread = one point = all 16 levels (fully unrolled -> deep gather ILP).
// Results staged in padded LDS [256][33] floats (write banks (t+2l)%32 ->
// conflict-free), then coalesced float4 epilogue (contiguous 1 KB per wave
// store). Eliminates the 256 MB tmp staging round-trip AND the assemble
// kernel's scattered-store transaction storm (64 lines per store instr).
// Trade-off: XCD table affinity lost; fine-level misses fall through to the
// 256 MB L3 which holds all 16 tables (64 MB).

#define NLEVELS 16
#define HASH_MASK 0x7FFFFu
#define TABLE_ENTRIES 524288  // 2^19 entries of float2 per level

struct ResTable { float r[NLEVELS]; };

__device__ __forceinline__ float2 level_gather(
    float x0, float x1, float x2,
    float xc0, float xc1, float xc2,
    const float2* __restrict__ tbl,
    float bmin0, float bmin1, float bmin2,
    float bmax0, float bmax1, float bmax2,
    float res)
{
    float g0 = (bmax0 - bmin0) / res;
    float g1 = (bmax1 - bmin1) / res;
    float g2 = (bmax2 - bmin2) / res;

    float f0 = floorf((xc0 - bmin0) / g0);
    float f1 = floorf((xc1 - bmin1) / g1);
    float f2 = floorf((xc2 - bmin2) / g2);
    int b0 = (int)f0, b1 = (int)f1, b2 = (int)f2;

    float vmin0 = f0 * g0 + bmin0;
    float vmin1 = f1 * g1 + bmin1;
    float vmin2 = f2 * g2 + bmin2;
    float wx = (x0 - vmin0) / g0;
    float wy = (x1 - vmin1) / g1;
    float wz = (x2 - vmin2) / g2;

    uint32_t hx0 = (uint32_t)b0;
    uint32_t hx1 = (uint32_t)(b0 + 1);
    uint32_t hy0 = (uint32_t)b1 * 2654435761u;
    uint32_t hy1 = (uint32_t)(b1 + 1) * 2654435761u;
    uint32_t hz0 = (uint32_t)b2 * 805459861u;
    uint32_t hz1 = (uint32_t)(b2 + 1) * 805459861u;

    float2 v0 = tbl[(hx0 ^ hy0 ^ hz0) & HASH_MASK];
    float2 v1 = tbl[(hx0 ^ hy0 ^ hz1) & HASH_MASK];
    float2 v2 = tbl[(hx0 ^ hy1 ^ hz0) & HASH_MASK];
    float2 v3 = tbl[(hx0 ^ hy1 ^ hz1) & HASH_MASK];
    float2 v4 = tbl[(hx1 ^ hy0 ^ hz0) & HASH_MASK];
    float2 v5 = tbl[(hx1 ^ hy0 ^ hz1) & HASH_MASK];
    float2 v6 = tbl[(hx1 ^ hy1 ^ hz0) & HASH_MASK];
    float2 v7 = tbl[(hx1 ^ hy1 ^ hz1) & HASH_MASK];

    float omx = 1.0f - wx, omy = 1.0f - wy, omz = 1.0f - wz;

    float c00_0 = v0.x * omx + v4.x * wx;
    float c00_1 = v0.y * omx + v4.y * wx;
    float c01_0 = v1.x * omx + v5.x * wx;
    float c01_1 = v1.y * omx + v5.y * wx;
    float c10_0 = v2.x * omx + v6.x * wx;
    float c10_1 = v2.y * omx + v6.y * wx;
    float c11_0 = v3.x * omx + v7.x * wx;
    float c11_1 = v3.y * omx + v7.y * wx;

    float c0_0 = c00_0 * omy + c10_0 * wy;
    float c0_1 = c00_1 * omy + c10_1 * wy;
    float c1_0 = c01_0 * omy + c11_0 * wy;
    float c1_1 = c01_1 * omy + c11_1 * wy;

    float2 o;
    o.x = c0_0 * omz + c1_0 * wz;
    o.y = c0_1 * omz + c1_1 * wz;
    return o;
}

// One point per thread, all 16 levels, LDS transpose, coalesced output.
__global__ __launch_bounds__(256, 4) void fused_hash_embed_kernel(
    const float* __restrict__ x,
    const float* __restrict__ emb,
    const float* __restrict__ bbox,
    float* __restrict__ out,
    float* __restrict__ mask,
    int n_points, ResTable rt)
{
    // Padded: stride 33 floats so per-level writes hit banks (t+2l)%32
    // (2 lanes/bank for wave64 = free) and epilogue reads are ~2-way.
    __shared__ float lds[256 * 33];

    const int tid = threadIdx.x;
    const int p0 = blockIdx.x * 256;
    const int p = p0 + tid;
    const bool active = (p < n_points);

    float bmin0 = bbox[0], bmin1 = bbox[1], bmin2 = bbox[2];
    float bmax0 = bbox[3], bmax1 = bbox[4], bmax2 = bbox[5];

    float x0 = bmin0, x1 = bmin1, x2 = bmin2;
    if (active) {
        const float* xp = x + (size_t)p * 3;
        x0 = xp[0]; x1 = xp[1]; x2 = xp[2];
        bool keep = (x0 >= bmin0) & (x0 <= bmax0) &
                    (x1 >= bmin1) & (x1 <= bmax1) &
                    (x2 >= bmin2) & (x2 <= bmax2);
        mask[p] = keep ? 1.0f : 0.0f;
    }

    // Clamp once; level-independent.
    float xc0 = fminf(fmaxf(x0, bmin0), bmax0);
    float xc1 = fminf(fmaxf(x1, bmin1), bmax1);
    float xc2 = fminf(fmaxf(x2, bmin2), bmax2);

#pragma unroll
    for (int l = 0; l < NLEVELS; ++l) {
        const float2* tbl = (const float2*)emb + (size_t)l * TABLE_ENTRIES;
        float2 o = level_gather(x0, x1, x2, xc0, xc1, xc2, tbl,
                                bmin0, bmin1, bmin2,
                                bmax0, bmax1, bmax2, rt.r[l]);
        lds[tid * 33 + 2 * l]     = o.x;
        lds[tid * 33 + 2 * l + 1] = o.y;
    }

    __syncthreads();

    // Coalesced epilogue: 2048 float4 per full block, contiguous.
    int nblk = n_points - p0;
    if (nblk > 256) nblk = 256;
    const int nfloat4 = nblk * 8;
    float4* dst = (float4*)(out + (size_t)p0 * 32);
#pragma unroll
    for (int j = 0; j < 8; ++j) {
        int v = j * 256 + tid;
        if (v < nfloat4) {
            int q = v >> 3;            // point within block
            int k = (v & 7) << 2;      // float offset within point's 32
            const float* s = &lds[q * 33 + k];
            dst[v] = make_float4(s[0], s[1], s[2], s[3]);
        }
    }
}

extern "C" void kernel_launch(void* const* d_in, const int* in_sizes, int n_in,
                              void* d_out, int out_size, void* d_ws, size_t ws_size,
                              hipStream_t stream) {
    const float* x    = (const float*)d_in[0];
    const float* emb  = (const float*)d_in[1];
    const float* bbox = (const float*)d_in[2];
    int n_points = in_sizes[0] / 3;

    float* out  = (float*)d_out;
    float* mask = out + (size_t)n_points * 32;

    // Host-side double libm matches numpy's resolution floor (levels
    // 3/6/9/12/15 are ulp-close to exact powers of two).
    ResTable rt;
    double b = exp((log(512.0) - log(16.0)) / 15.0);
    for (int l = 0; l < NLEVELS; ++l)
        rt.r[l] = (float)floor(16.0 * pow(b, (double)l));

    int blocks = (n_points + 255) / 256;
    hipLaunchKernelGGL(fused_hash_embed_kernel, dim3(blocks), dim3(256), 0,
                       stream, x, emb, bbox, out, mask, n_points, rt);
}

// Round 2
// 593.283 us; speedup vs baseline: 1.3390x; 1.3390x over previous
//
#include <hip/hip_runtime.h>
#include <math.h>
#include <stdint.h>

// HashEmbedder, round 4: XCD-affine partition (round 2) + compact coarse
// tables + LDS-transposed assemble.
//
// Post-mortem r3: fusion lost XCD table affinity -> FETCH 0.23->2.2 GB,
// L2 req throughput 15.4 -> 10 /cyc/XCD. Partition restored.
// New: the hash scatters even coarse grids across the full 4 MB table, so
// EVERY level was L2-request-bound (phase A == phase B == 216 us). For
// levels 0-7 ((res+2)^3 fits <= 4.4 MB) a prepass builds linearly-indexed
// compact tables: z-pair corners become adjacent float2 (TCP merges the
// pair -> one L2 fill), 8 corners span ~4-5 lines not 8 -> ~1.8x fewer L2
// requests for the coarse half. Levels 8-15 stay hashed (true roofline).
// Assemble now stages through padded LDS (r3's proven conflict-free
// epilogue) -> contiguous float4 stores instead of 64-lines-per-store.

#define NLEVELS 16
#define HASH_MASK 0x7FFFFu
#define TABLE_ENTRIES 524288  // 2^19 float2 entries per level

struct ResTable { float r[NLEVELS]; };
struct CompactMeta { int dim[8]; int off[8]; };  // off = float2-entry offset

// ---------------------------------------------------------------- hashed path
__device__ __forceinline__ float2 gather_one_level(
    const float* __restrict__ x, const float2* __restrict__ tbl,
    float bmin0, float bmin1, float bmin2,
    float bmax0, float bmax1, float bmax2,
    float res, int point)
{
    const float* xp = x + (size_t)point * 3;
    float x0 = xp[0], x1 = xp[1], x2 = xp[2];

    float xc0 = fminf(fmaxf(x0, bmin0), bmax0);
    float xc1 = fminf(fmaxf(x1, bmin1), bmax1);
    float xc2 = fminf(fmaxf(x2, bmin2), bmax2);

    float g0 = (bmax0 - bmin0) / res;
    float g1 = (bmax1 - bmin1) / res;
    float g2 = (bmax2 - bmin2) / res;

    float f0 = floorf((xc0 - bmin0) / g0);
    float f1 = floorf((xc1 - bmin1) / g1);
    float f2 = floorf((xc2 - bmin2) / g2);
    int b0 = (int)f0, b1 = (int)f1, b2 = (int)f2;

    float vmin0 = f0 * g0 + bmin0;
    float vmin1 = f1 * g1 + bmin1;
    float vmin2 = f2 * g2 + bmin2;
    float wx = (x0 - vmin0) / g0;
    float wy = (x1 - vmin1) / g1;
    float wz = (x2 - vmin2) / g2;

    uint32_t hx0 = (uint32_t)b0;
    uint32_t hx1 = (uint32_t)(b0 + 1);
    uint32_t hy0 = (uint32_t)b1 * 2654435761u;
    uint32_t hy1 = (uint32_t)(b1 + 1) * 2654435761u;
    uint32_t hz0 = (uint32_t)b2 * 805459861u;
    uint32_t hz1 = (uint32_t)(b2 + 1) * 805459861u;

    float2 v0 = tbl[(hx0 ^ hy0 ^ hz0) & HASH_MASK];
    float2 v1 = tbl[(hx0 ^ hy0 ^ hz1) & HASH_MASK];
    float2 v2 = tbl[(hx0 ^ hy1 ^ hz0) & HASH_MASK];
    float2 v3 = tbl[(hx0 ^ hy1 ^ hz1) & HASH_MASK];
    float2 v4 = tbl[(hx1 ^ hy0 ^ hz0) & HASH_MASK];
    float2 v5 = tbl[(hx1 ^ hy0 ^ hz1) & HASH_MASK];
    float2 v6 = tbl[(hx1 ^ hy1 ^ hz0) & HASH_MASK];
    float2 v7 = tbl[(hx1 ^ hy1 ^ hz1) & HASH_MASK];

    float omx = 1.0f - wx, omy = 1.0f - wy, omz = 1.0f - wz;

    float c00_0 = v0.x * omx + v4.x * wx;
    float c00_1 = v0.y * omx + v4.y * wx;
    float c01_0 = v1.x * omx + v5.x * wx;
    float c01_1 = v1.y * omx + v5.y * wx;
    float c10_0 = v2.x * omx + v6.x * wx;
    float c10_1 = v2.y * omx + v6.y * wx;
    float c11_0 = v3.x * omx + v7.x * wx;
    float c11_1 = v3.y * omx + v7.y * wx;

    float c0_0 = c00_0 * omy + c10_0 * wy;
    float c0_1 = c00_1 * omy + c10_1 * wy;
    float c1_0 = c01_0 * omy + c11_0 * wy;
    float c1_1 = c01_1 * omy + c11_1 * wy;

    float2 o;
    o.x = c0_0 * omz + c1_0 * wz;
    o.y = c0_1 * omz + c1_1 * wz;
    return o;
}

// Hashed levels: level = blockIdx&7 + base rides round-robin block->XCD
// dispatch so each XCD's gather set is ONE 4 MB table -> L2-resident.
__global__ __launch_bounds__(256) void gather_level_kernel(
    const float* __restrict__ x,
    const float* __restrict__ emb,
    const float* __restrict__ bbox,
    float2* __restrict__ tmp,   // [NLEVELS][n_points]
    int n_points, int level_base, ResTable rt)
{
    int level = (blockIdx.x & 7) + level_base;
    int point = (blockIdx.x >> 3) * 256 + threadIdx.x;
    if (point >= n_points) return;

    float bmin0 = bbox[0], bmin1 = bbox[1], bmin2 = bbox[2];
    float bmax0 = bbox[3], bmax1 = bbox[4], bmax2 = bbox[5];

    const float2* tbl = (const float2*)emb + (size_t)level * TABLE_ENTRIES;
    float2 o = gather_one_level(x, tbl, bmin0, bmin1, bmin2,
                                bmax0, bmax1, bmax2, rt.r[level], point);
    tmp[(size_t)level * n_points + point] = o;
}

// ---------------------------------------------------------------- compact path
// Prepass: de-scatter coarse tables. compact[off[l] + (i*D + j)*D + k] =
// tbl_l[hash(i,j,k) & MASK], D = res+2 (corners reach res+1 at the clamp
// boundary). ~1.13M entries total -> ~10 us.
__global__ __launch_bounds__(256) void build_compact_kernel(
    const float* __restrict__ emb,
    float2* __restrict__ compact,
    CompactMeta cm, int total)
{
    int id = blockIdx.x * 256 + threadIdx.x;
    if (id >= total) return;

    int l = 0;
#pragma unroll
    for (int t = 1; t < 8; ++t)
        if (id >= cm.off[t]) l = t;
    int local = id - cm.off[l];
    int D = cm.dim[l];

    int k = local % D;
    int t2 = local / D;
    int j = t2 % D;
    int i = t2 / D;

    uint32_t h = (uint32_t)i
               ^ ((uint32_t)j * 2654435761u)
               ^ ((uint32_t)k * 805459861u);
    const float2* tbl = (const float2*)emb + (size_t)l * TABLE_ENTRIES;
    compact[id] = tbl[h & HASH_MASK];
}

// Coarse levels 0-7 from compact tables. Same XCD affinity (level=blockIdx&7;
// per-XCD working set = one compact table <= 4.4 MB). z-pair loads (base,
// base+1) hit the same 64B line 7/8 of the time -> TCP merges them.
__global__ __launch_bounds__(256) void gather_compact_kernel(
    const float* __restrict__ x,
    const float2* __restrict__ compact,
    const float* __restrict__ bbox,
    float2* __restrict__ tmp,
    int n_points, CompactMeta cm, ResTable rt)
{
    int level = blockIdx.x & 7;
    int point = (blockIdx.x >> 3) * 256 + threadIdx.x;
    if (point >= n_points) return;

    float bmin0 = bbox[0], bmin1 = bbox[1], bmin2 = bbox[2];
    float bmax0 = bbox[3], bmax1 = bbox[4], bmax2 = bbox[5];
    float res = rt.r[level];

    const float* xp = x + (size_t)point * 3;
    float x0 = xp[0], x1 = xp[1], x2 = xp[2];

    float xc0 = fminf(fmaxf(x0, bmin0), bmax0);
    float xc1 = fminf(fmaxf(x1, bmin1), bmax1);
    float xc2 = fminf(fmaxf(x2, bmin2), bmax2);

    float g0 = (bmax0 - bmin0) / res;
    float g1 = (bmax1 - bmin1) / res;
    float g2 = (bmax2 - bmin2) / res;

    float f0 = floorf((xc0 - bmin0) / g0);
    float f1 = floorf((xc1 - bmin1) / g1);
    float f2 = floorf((xc2 - bmin2) / g2);
    int b0 = (int)f0, b1 = (int)f1, b2 = (int)f2;

    float vmin0 = f0 * g0 + bmin0;
    float vmin1 = f1 * g1 + bmin1;
    float vmin2 = f2 * g2 + bmin2;
    float wx = (x0 - vmin0) / g0;
    float wy = (x1 - vmin1) / g1;
    float wz = (x2 - vmin2) / g2;

    int D = cm.dim[level];
    const float2* tb = compact + cm.off[level];
    int base = (b0 * D + b1) * D + b2;
    int dj = D;        // +1 in j
    int di = D * D;    // +1 in i

    // Corner order matches reference OFFSETS (i,j,k) = bit 4,2,1 of index.
    float2 v0 = tb[base];
    float2 v1 = tb[base + 1];
    float2 v2 = tb[base + dj];
    float2 v3 = tb[base + dj + 1];
    float2 v4 = tb[base + di];
    float2 v5 = tb[base + di + 1];
    float2 v6 = tb[base + di + dj];
    float2 v7 = tb[base + di + dj + 1];

    float omx = 1.0f - wx, omy = 1.0f - wy, omz = 1.0f - wz;

    float c00_0 = v0.x * omx + v4.x * wx;
    float c00_1 = v0.y * omx + v4.y * wx;
    float c01_0 = v1.x * omx + v5.x * wx;
    float c01_1 = v1.y * omx + v5.y * wx;
    float c10_0 = v2.x * omx + v6.x * wx;
    float c10_1 = v2.y * omx + v6.y * wx;
    float c11_0 = v3.x * omx + v7.x * wx;
    float c11_1 = v3.y * omx + v7.y * wx;

    float c0_0 = c00_0 * omy + c10_0 * wy;
    float c0_1 = c00_1 * omy + c10_1 * wy;
    float c1_0 = c01_0 * omy + c11_0 * wy;
    float c1_1 = c01_1 * omy + c11_1 * wy;

    float2 o;
    o.x = c0_0 * omz + c1_0 * wz;
    o.y = c0_1 * omz + c1_1 * wz;
    tmp[(size_t)level * n_points + point] = o;
}

// ---------------------------------------------------------------- assemble
// LDS transpose (r3's proven conflict-free epilogue): coalesced level-major
// reads -> padded LDS [256][33] -> contiguous float4 stores (1 KB/wave).
__global__ __launch_bounds__(256) void assemble_lds_kernel(
    const float* __restrict__ x,
    const float2* __restrict__ tmp,
    const float* __restrict__ bbox,
    float* __restrict__ out,
    float* __restrict__ mask,
    int n_points)
{
    __shared__ float lds[256 * 33];

    const int tid = threadIdx.x;
    const int p0 = blockIdx.x * 256;
    const int p = p0 + tid;

    if (p < n_points) {
#pragma unroll
        for (int l = 0; l < NLEVELS; ++l) {
            float2 v = tmp[(size_t)l * n_points + p];
            lds[tid * 33 + 2 * l]     = v.x;
            lds[tid * 33 + 2 * l + 1] = v.y;
        }
        float bmin0 = bbox[0], bmin1 = bbox[1], bmin2 = bbox[2];
        float bmax0 = bbox[3], bmax1 = bbox[4], bmax2 = bbox[5];
        const float* xp = x + (size_t)p * 3;
        float x0 = xp[0], x1 = xp[1], x2 = xp[2];
        bool keep = (x0 >= bmin0) & (x0 <= bmax0) &
                    (x1 >= bmin1) & (x1 <= bmax1) &
                    (x2 >= bmin2) & (x2 <= bmax2);
        mask[p] = keep ? 1.0f : 0.0f;
    }

    __syncthreads();

    int nblk = n_points - p0;
    if (nblk > 256) nblk = 256;
    const int nfloat4 = nblk * 8;
    float4* dst = (float4*)(out + (size_t)p0 * 32);
#pragma unroll
    for (int j = 0; j < 8; ++j) {
        int v = j * 256 + tid;
        if (v < nfloat4) {
            int q = v >> 3;
            int k = (v & 7) << 2;
            const float* s = &lds[q * 33 + k];
            dst[v] = make_float4(s[0], s[1], s[2], s[3]);
        }
    }
}

// ---------------------------------------------------------------- fallback
__global__ __launch_bounds__(256) void hash_embed_direct_kernel(
    const float* __restrict__ x,
    const float* __restrict__ emb,
    const float* __restrict__ bbox,
    float* __restrict__ out,
    float* __restrict__ mask,
    int n_points, ResTable rt)
{
    int tid = blockIdx.x * 256 + threadIdx.x;
    int point = tid >> 4;
    int level = tid & 15;
    if (point >= n_points) return;

    float bmin0 = bbox[0], bmin1 = bbox[1], bmin2 = bbox[2];
    float bmax0 = bbox[3], bmax1 = bbox[4], bmax2 = bbox[5];

    if (level == 0) {
        const float* xp = x + (size_t)point * 3;
        float x0 = xp[0], x1 = xp[1], x2 = xp[2];
        bool keep = (x0 >= bmin0) & (x0 <= bmax0) &
                    (x1 >= bmin1) & (x1 <= bmax1) &
                    (x2 >= bmin2) & (x2 <= bmax2);
        mask[point] = keep ? 1.0f : 0.0f;
    }

    const float2* tbl = (const float2*)emb + (size_t)level * TABLE_ENTRIES;
    float2 o = gather_one_level(x, tbl, bmin0, bmin1, bmin2,
                                bmax0, bmax1, bmax2, rt.r[level], point);
    *(float2*)(out + (size_t)point * 32 + level * 2) = o;
}

// ---------------------------------------------------------------- launch
extern "C" void kernel_launch(void* const* d_in, const int* in_sizes, int n_in,
                              void* d_out, int out_size, void* d_ws, size_t ws_size,
                              hipStream_t stream) {
    const float* x    = (const float*)d_in[0];
    const float* emb  = (const float*)d_in[1];
    const float* bbox = (const float*)d_in[2];
    int n_points = in_sizes[0] / 3;

    float* out  = (float*)d_out;
    float* mask = out + (size_t)n_points * 32;

    // Host-side double libm matches numpy's resolution floor (levels
    // 3/6/9/12/15 are ulp-close to exact powers of two).
    ResTable rt;
    double b = exp((log(512.0) - log(16.0)) / 15.0);
    for (int l = 0; l < NLEVELS; ++l)
        rt.r[l] = (float)floor(16.0 * pow(b, (double)l));

    // Compact-table geometry for levels 0-7: D = res+2 covers corner = res+1
    // at the xc==bmax clamp boundary.
    CompactMeta cm;
    int total_compact = 0;
    for (int l = 0; l < 8; ++l) {
        int D = (int)rt.r[l] + 2;
        cm.dim[l] = D;
        cm.off[l] = total_compact;
        total_compact += D * D * D;
    }
    size_t tmp_bytes = (size_t)n_points * NLEVELS * sizeof(float2);
    size_t compact_bytes = (size_t)total_compact * sizeof(float2);

    int chunks = (n_points + 255) / 256;

    if (ws_size >= tmp_bytes + compact_bytes) {
        float2* tmp = (float2*)d_ws;
        float2* compact = (float2*)((char*)d_ws + tmp_bytes);

        int pre_blocks = (total_compact + 255) / 256;
        hipLaunchKernelGGL(build_compact_kernel, dim3(pre_blocks), dim3(256),
                           0, stream, emb, compact, cm, total_compact);

        dim3 grid(chunks * 8);
        // Hashed fine levels 8-15: one table per XCD, L2-resident.
        hipLaunchKernelGGL(gather_level_kernel, grid, dim3(256), 0, stream,
                           x, emb, bbox, tmp, n_points, 8, rt);
        // Compact coarse levels 0-7: one compact table per XCD.
        hipLaunchKernelGGL(gather_compact_kernel, grid, dim3(256), 0, stream,
                           x, compact, bbox, tmp, n_points, cm, rt);

        hipLaunchKernelGGL(assemble_lds_kernel, dim3(chunks), dim3(256), 0,
                           stream, x, tmp, bbox, out, mask, n_points);
    } else if (ws_size >= tmp_bytes) {
        // Mid tier: round-2 gathers + improved assemble.
        float2* tmp = (float2*)d_ws;
        dim3 grid(chunks * 8);
        hipLaunchKernelGGL(gather_level_kernel, grid, dim3(256), 0, stream,
                           x, emb, bbox, tmp, n_points, 0, rt);
        hipLaunchKernelGGL(gather_level_kernel, grid, dim3(256), 0, stream,
                           x, emb, bbox, tmp, n_points, 8, rt);
        hipLaunchKernelGGL(assemble_lds_kernel, dim3(chunks), dim3(256), 0,
                           stream, x, tmp, bbox, out, mask, n_points);
    } else {
        long long total = (long long)n_points * NLEVELS;
        int blocks = (int)((total + 255) / 256);
        hipLaunchKernelGGL(hash_embed_direct_kernel, dim3(blocks), dim3(256), 0,
                           stream, x, emb, bbox, out, mask, n_points, rt);
    }
}

// Round 3
// 592.803 us; speedup vs baseline: 1.3401x; 1.0008x over previous
//
#include <hip/hip_runtime.h>
#include <math.h>
#include <stdint.h>

// HashEmbedder, round 5: compact coarse tables with SINGLE-INSTRUCTION z-pair
// loads (dwordx4), XCD-affine partition, LDS-transposed assemble.
//
// Post-mortem r4: TA merges same-line lane requests only WITHIN one
// instruction. tb[base] / tb[base+1] as two dwordx2 instructions cost two L2
// requests per lane -> compact phase issued the same 8 req/point as the
// hashed phase; both sit at the measured 15.4 req/cyc/XCD L2 ceiling
// (16-channel request rate). Fix: load each z-pair as ONE 16-byte load
// (align-8 struct -> global_load_dwordx4; gfx9+ allows dword-aligned
// multi-dword loads). 8 -> 4 requests/point for levels 0-7.
// Levels 8-15 (hash-scattered, no contiguity) stay at their 8-req/point
// structural floor: 64M req / (8 XCD * 16/cyc) = ~218 us. Accepted.

#define NLEVELS 16
#define HASH_MASK 0x7FFFFu
#define TABLE_ENTRIES 524288  // 2^19 float2 entries per level

struct ResTable { float r[NLEVELS]; };
struct CompactMeta { int dim[8]; int off[8]; };  // off = float2-entry offset

// 16-byte z-pair: cells (k, k+1) of one (i,j) row. align(8) is truthful
// (entries are float2-aligned); AMDGPU emits one dwordx4 regardless.
struct __align__(8) ZPair { float ax, ay, bx, by; };

// ---------------------------------------------------------------- hashed path
__device__ __forceinline__ float2 gather_one_level(
    const float* __restrict__ x, const float2* __restrict__ tbl,
    float bmin0, float bmin1, float bmin2,
    float bmax0, float bmax1, float bmax2,
    float res, int point)
{
    const float* xp = x + (size_t)point * 3;
    float x0 = xp[0], x1 = xp[1], x2 = xp[2];

    float xc0 = fminf(fmaxf(x0, bmin0), bmax0);
    float xc1 = fminf(fmaxf(x1, bmin1), bmax1);
    float xc2 = fminf(fmaxf(x2, bmin2), bmax2);

    float g0 = (bmax0 - bmin0) / res;
    float g1 = (bmax1 - bmin1) / res;
    float g2 = (bmax2 - bmin2) / res;

    float f0 = floorf((xc0 - bmin0) / g0);
    float f1 = floorf((xc1 - bmin1) / g1);
    float f2 = floorf((xc2 - bmin2) / g2);
    int b0 = (int)f0, b1 = (int)f1, b2 = (int)f2;

    float vmin0 = f0 * g0 + bmin0;
    float vmin1 = f1 * g1 + bmin1;
    float vmin2 = f2 * g2 + bmin2;
    float wx = (x0 - vmin0) / g0;
    float wy = (x1 - vmin1) / g1;
    float wz = (x2 - vmin2) / g2;

    uint32_t hx0 = (uint32_t)b0;
    uint32_t hx1 = (uint32_t)(b0 + 1);
    uint32_t hy0 = (uint32_t)b1 * 2654435761u;
    uint32_t hy1 = (uint32_t)(b1 + 1) * 2654435761u;
    uint32_t hz0 = (uint32_t)b2 * 805459861u;
    uint32_t hz1 = (uint32_t)(b2 + 1) * 805459861u;

    float2 v0 = tbl[(hx0 ^ hy0 ^ hz0) & HASH_MASK];
    float2 v1 = tbl[(hx0 ^ hy0 ^ hz1) & HASH_MASK];
    float2 v2 = tbl[(hx0 ^ hy1 ^ hz0) & HASH_MASK];
    float2 v3 = tbl[(hx0 ^ hy1 ^ hz1) & HASH_MASK];
    float2 v4 = tbl[(hx1 ^ hy0 ^ hz0) & HASH_MASK];
    float2 v5 = tbl[(hx1 ^ hy0 ^ hz1) & HASH_MASK];
    float2 v6 = tbl[(hx1 ^ hy1 ^ hz0) & HASH_MASK];
    float2 v7 = tbl[(hx1 ^ hy1 ^ hz1) & HASH_MASK];

    float omx = 1.0f - wx, omy = 1.0f - wy, omz = 1.0f - wz;

    float c00_0 = v0.x * omx + v4.x * wx;
    float c00_1 = v0.y * omx + v4.y * wx;
    float c01_0 = v1.x * omx + v5.x * wx;
    float c01_1 = v1.y * omx + v5.y * wx;
    float c10_0 = v2.x * omx + v6.x * wx;
    float c10_1 = v2.y * omx + v6.y * wx;
    float c11_0 = v3.x * omx + v7.x * wx;
    float c11_1 = v3.y * omx + v7.y * wx;

    float c0_0 = c00_0 * omy + c10_0 * wy;
    float c0_1 = c00_1 * omy + c10_1 * wy;
    float c1_0 = c01_0 * omy + c11_0 * wy;
    float c1_1 = c01_1 * omy + c11_1 * wy;

    float2 o;
    o.x = c0_0 * omz + c1_0 * wz;
    o.y = c0_1 * omz + c1_1 * wz;
    return o;
}

// Hashed levels: level = blockIdx&7 + base rides round-robin block->XCD
// dispatch so each XCD's gather set is ONE 4 MB table -> L2-resident.
__global__ __launch_bounds__(256) void gather_level_kernel(
    const float* __restrict__ x,
    const float* __restrict__ emb,
    const float* __restrict__ bbox,
    float2* __restrict__ tmp,   // [NLEVELS][n_points]
    int n_points, int level_base, ResTable rt)
{
    int level = (blockIdx.x & 7) + level_base;
    int point = (blockIdx.x >> 3) * 256 + threadIdx.x;
    if (point >= n_points) return;

    float bmin0 = bbox[0], bmin1 = bbox[1], bmin2 = bbox[2];
    float bmax0 = bbox[3], bmax1 = bbox[4], bmax2 = bbox[5];

    const float2* tbl = (const float2*)emb + (size_t)level * TABLE_ENTRIES;
    float2 o = gather_one_level(x, tbl, bmin0, bmin1, bmin2,
                                bmax0, bmax1, bmax2, rt.r[level], point);
    tmp[(size_t)level * n_points + point] = o;
}

// ---------------------------------------------------------------- compact path
// Prepass: de-scatter coarse tables. compact[off[l] + (i*D + j)*D + k] =
// tbl_l[hash(i,j,k) & MASK], D = res+2 (corners reach res+1 at the clamp
// boundary). ~1.13M entries -> ~10 us.
__global__ __launch_bounds__(256) void build_compact_kernel(
    const float* __restrict__ emb,
    float2* __restrict__ compact,
    CompactMeta cm, int total)
{
    int id = blockIdx.x * 256 + threadIdx.x;
    if (id >= total) return;

    int l = 0;
#pragma unroll
    for (int t = 1; t < 8; ++t)
        if (id >= cm.off[t]) l = t;
    int local = id - cm.off[l];
    int D = cm.dim[l];

    int k = local % D;
    int t2 = local / D;
    int j = t2 % D;
    int i = t2 / D;

    uint32_t h = (uint32_t)i
               ^ ((uint32_t)j * 2654435761u)
               ^ ((uint32_t)k * 805459861u);
    const float2* tbl = (const float2*)emb + (size_t)l * TABLE_ENTRIES;
    compact[id] = tbl[h & HASH_MASK];
}

// Coarse levels 0-7: XCD-affine (level=blockIdx&7), compact tables, and the
// z-pair of each (i,j) row loaded as ONE dwordx4 -> 4 L2 requests/point.
__global__ __launch_bounds__(256) void gather_compact_kernel(
    const float* __restrict__ x,
    const float2* __restrict__ compact,
    const float* __restrict__ bbox,
    float2* __restrict__ tmp,
    int n_points, CompactMeta cm, ResTable rt)
{
    int level = blockIdx.x & 7;
    int point = (blockIdx.x >> 3) * 256 + threadIdx.x;
    if (point >= n_points) return;

    float bmin0 = bbox[0], bmin1 = bbox[1], bmin2 = bbox[2];
    float bmax0 = bbox[3], bmax1 = bbox[4], bmax2 = bbox[5];
    float res = rt.r[level];

    const float* xp = x + (size_t)point * 3;
    float x0 = xp[0], x1 = xp[1], x2 = xp[2];

    float xc0 = fminf(fmaxf(x0, bmin0), bmax0);
    float xc1 = fminf(fmaxf(x1, bmin1), bmax1);
    float xc2 = fminf(fmaxf(x2, bmin2), bmax2);

    float g0 = (bmax0 - bmin0) / res;
    float g1 = (bmax1 - bmin1) / res;
    float g2 = (bmax2 - bmin2) / res;

    float f0 = floorf((xc0 - bmin0) / g0);
    float f1 = floorf((xc1 - bmin1) / g1);
    float f2 = floorf((xc2 - bmin2) / g2);
    int b0 = (int)f0, b1 = (int)f1, b2 = (int)f2;

    float vmin0 = f0 * g0 + bmin0;
    float vmin1 = f1 * g1 + bmin1;
    float vmin2 = f2 * g2 + bmin2;
    float wx = (x0 - vmin0) / g0;
    float wy = (x1 - vmin1) / g1;
    float wz = (x2 - vmin2) / g2;

    int D = cm.dim[level];
    const float2* tb = compact + cm.off[level];
    int base = (b0 * D + b1) * D + b2;
    int dj = D;        // +1 in j
    int di = D * D;    // +1 in i

    // One 16B load per (i,j) row = z-cells (k, k+1) in one instruction.
    ZPair q0 = *(const ZPair*)(tb + base);            // (i0,j0)
    ZPair q2 = *(const ZPair*)(tb + base + dj);       // (i0,j1)
    ZPair q4 = *(const ZPair*)(tb + base + di);       // (i1,j0)
    ZPair q6 = *(const ZPair*)(tb + base + di + dj);  // (i1,j1)

    float omx = 1.0f - wx, omy = 1.0f - wy, omz = 1.0f - wz;

    // Corner order matches reference OFFSETS (i,j,k) = bit 4,2,1 of index:
    // v0=q0.a v1=q0.b v2=q2.a v3=q2.b v4=q4.a v5=q4.b v6=q6.a v7=q6.b
    float c00_0 = q0.ax * omx + q4.ax * wx;
    float c00_1 = q0.ay * omx + q4.ay * wx;
    float c01_0 = q0.bx * omx + q4.bx * wx;
    float c01_1 = q0.by * omx + q4.by * wx;
    float c10_0 = q2.ax * omx + q6.ax * wx;
    float c10_1 = q2.ay * omx + q6.ay * wx;
    float c11_0 = q2.bx * omx + q6.bx * wx;
    float c11_1 = q2.by * omx + q6.by * wx;

    float c0_0 = c00_0 * omy + c10_0 * wy;
    float c0_1 = c00_1 * omy + c10_1 * wy;
    float c1_0 = c01_0 * omy + c11_0 * wy;
    float c1_1 = c01_1 * omy + c11_1 * wy;

    float2 o;
    o.x = c0_0 * omz + c1_0 * wz;
    o.y = c0_1 * omz + c1_1 * wz;
    tmp[(size_t)level * n_points + point] = o;
}

// ---------------------------------------------------------------- assemble
// LDS transpose: coalesced level-major reads -> padded LDS [256][33] ->
// contiguous float4 stores (1 KB/wave). Bank-conflict-free both phases.
__global__ __launch_bounds__(256) void assemble_lds_kernel(
    const float* __restrict__ x,
    const float2* __restrict__ tmp,
    const float* __restrict__ bbox,
    float* __restrict__ out,
    float* __restrict__ mask,
    int n_points)
{
    __shared__ float lds[256 * 33];

    const int tid = threadIdx.x;
    const int p0 = blockIdx.x * 256;
    const int p = p0 + tid;

    if (p < n_points) {
#pragma unroll
        for (int l = 0; l < NLEVELS; ++l) {
            float2 v = tmp[(size_t)l * n_points + p];
            lds[tid * 33 + 2 * l]     = v.x;
            lds[tid * 33 + 2 * l + 1] = v.y;
        }
        float bmin0 = bbox[0], bmin1 = bbox[1], bmin2 = bbox[2];
        float bmax0 = bbox[3], bmax1 = bbox[4], bmax2 = bbox[5];
        const float* xp = x + (size_t)p * 3;
        float x0 = xp[0], x1 = xp[1], x2 = xp[2];
        bool keep = (x0 >= bmin0) & (x0 <= bmax0) &
                    (x1 >= bmin1) & (x1 <= bmax1) &
                    (x2 >= bmin2) & (x2 <= bmax2);
        mask[p] = keep ? 1.0f : 0.0f;
    }

    __syncthreads();

    int nblk = n_points - p0;
    if (nblk > 256) nblk = 256;
    const int nfloat4 = nblk * 8;
    float4* dst = (float4*)(out + (size_t)p0 * 32);
#pragma unroll
    for (int j = 0; j < 8; ++j) {
        int v = j * 256 + tid;
        if (v < nfloat4) {
            int q = v >> 3;
            int k = (v & 7) << 2;
            const float* s = &lds[q * 33 + k];
            dst[v] = make_float4(s[0], s[1], s[2], s[3]);
        }
    }
}

// ---------------------------------------------------------------- fallback
__global__ __launch_bounds__(256) void hash_embed_direct_kernel(
    const float* __restrict__ x,
    const float* __restrict__ emb,
    const float* __restrict__ bbox,
    float* __restrict__ out,
    float* __restrict__ mask,
    int n_points, ResTable rt)
{
    int tid = blockIdx.x * 256 + threadIdx.x;
    int point = tid >> 4;
    int level = tid & 15;
    if (point >= n_points) return;

    float bmin0 = bbox[0], bmin1 = bbox[1], bmin2 = bbox[2];
    float bmax0 = bbox[3], bmax1 = bbox[4], bmax2 = bbox[5];

    if (level == 0) {
        const float* xp = x + (size_t)point * 3;
        float x0 = xp[0], x1 = xp[1], x2 = xp[2];
        bool keep = (x0 >= bmin0) & (x0 <= bmax0) &
                    (x1 >= bmin1) & (x1 <= bmax1) &
                    (x2 >= bmin2) & (x2 <= bmax2);
        mask[point] = keep ? 1.0f : 0.0f;
    }

    const float2* tbl = (const float2*)emb + (size_t)level * TABLE_ENTRIES;
    float2 o = gather_one_level(x, tbl, bmin0, bmin1, bmin2,
                                bmax0, bmax1, bmax2, rt.r[level], point);
    *(float2*)(out + (size_t)point * 32 + level * 2) = o;
}

// ---------------------------------------------------------------- launch
extern "C" void kernel_launch(void* const* d_in, const int* in_sizes, int n_in,
                              void* d_out, int out_size, void* d_ws, size_t ws_size,
                              hipStream_t stream) {
    const float* x    = (const float*)d_in[0];
    const float* emb  = (const float*)d_in[1];
    const float* bbox = (const float*)d_in[2];
    int n_points = in_sizes[0] / 3;

    float* out  = (float*)d_out;
    float* mask = out + (size_t)n_points * 32;

    // Host-side double libm matches numpy's resolution floor (levels
    // 3/6/9/12/15 are ulp-close to exact powers of two).
    ResTable rt;
    double b = exp((log(512.0) - log(16.0)) / 15.0);
    for (int l = 0; l < NLEVELS; ++l)
        rt.r[l] = (float)floor(16.0 * pow(b, (double)l));

    // Compact-table geometry for levels 0-7: D = res+2 covers corner = res+1
    // at the xc==bmax clamp boundary.
    CompactMeta cm;
    int total_compact = 0;
    for (int l = 0; l < 8; ++l) {
        int D = (int)rt.r[l] + 2;
        cm.dim[l] = D;
        cm.off[l] = total_compact;
        total_compact += D * D * D;
    }
    // +2 entries of slack so the final row's 16B z-pair load can't run off
    // the buffer end.
    size_t tmp_bytes = (size_t)n_points * NLEVELS * sizeof(float2);
    size_t compact_bytes = (size_t)(total_compact + 2) * sizeof(float2);

    int chunks = (n_points + 255) / 256;

    if (ws_size >= tmp_bytes + compact_bytes) {
        float2* tmp = (float2*)d_ws;
        float2* compact = (float2*)((char*)d_ws + tmp_bytes);

        int pre_blocks = (total_compact + 255) / 256;
        hipLaunchKernelGGL(build_compact_kernel, dim3(pre_blocks), dim3(256),
                           0, stream, emb, compact, cm, total_compact);

        dim3 grid(chunks * 8);
        // Hashed fine levels 8-15: one table per XCD, L2-resident.
        hipLaunchKernelGGL(gather_level_kernel, grid, dim3(256), 0, stream,
                           x, emb, bbox, tmp, n_points, 8, rt);
        // Compact coarse levels 0-7: one compact table per XCD, paired loads.
        hipLaunchKernelGGL(gather_compact_kernel, grid, dim3(256), 0, stream,
                           x, compact, bbox, tmp, n_points, cm, rt);

        hipLaunchKernelGGL(assemble_lds_kernel, dim3(chunks), dim3(256), 0,
                           stream, x, tmp, bbox, out, mask, n_points);
    } else if (ws_size >= tmp_bytes) {
        float2* tmp = (float2*)d_ws;
        dim3 grid(chunks * 8);
        hipLaunchKernelGGL(gather_level_kernel, grid, dim3(256), 0, stream,
                           x, emb, bbox, tmp, n_points, 0, rt);
        hipLaunchKernelGGL(gather_level_kernel, grid, dim3(256), 0, stream,
                           x, emb, bbox, tmp, n_points, 8, rt);
        hipLaunchKernelGGL(assemble_lds_kernel, dim3(chunks), dim3(256), 0,
                           stream, x, tmp, bbox, out, mask, n_points);
    } else {
        long long total = (long long)n_points * NLEVELS;
        int blocks = (int)((total + 255) / 256);
        hipLaunchKernelGGL(hash_embed_direct_kernel, dim3(blocks), dim3(256), 0,
                           stream, x, emb, bbox, out, mask, n_points, rt);
    }
}